// Round 16
// baseline (156.068 us; speedup 1.0000x reference)
//
#include <hip/hip_runtime.h>
#include <math.h>

// GEBLNet via Gram-matrix reduction (R16 = R14 + single-pass layer 1).
//   T[u] = sum_{v,w} w2[u,v,w] * tr(We2[v] @ We2[w]) -> 169 unique Gram values,
//   w2 folded per-launch into CTt[169][12] float4 (setup kernel; ~40-50us
//   bench-vs-main gap is fixed harness overhead, extra dispatch is free).
// Shape (R10/R14-proven): 8192 blocks x 64 threads, 1 wave = 1 point.
// Layer 1 on all 64 lanes, ONE pass through a 12.5KB LDS B buffer:
//   2a: job=(u,v,jk): B[u,v,jk] = sum_w w1[u,v,w]*We[w,jk]
//       1404 jobs, 21-22/lane, one uninterrupted load/FMA stream.
//   2b: job=(u,ik):  H[u,ik] = sum_{v,j} We[v,i,j]*B[u,v,j*3+k]  (108 jobs)
// R16 rationale: R14 ran 82us at VALUBusy 55% vs ~25us issue floor ->
// stall-bound; the two u-half passes (4 barriers) chopped 2a into short
// load-wait segments. Merging halves the barrier count and doubles the
// independent loads in flight per segment + doubles 2b lane utilization.
// LESSON (R15): fine-grained 1-cmac jobs beat wider-job mappings (balance);
// the SQ_LDS_BANK_CONFLICT counts here are benign 2-way aliasing.
// LESSON (R13): VGPR>64 costs occupancy; keep w-loop #pragma unroll 1.
// LESSON (R12): multi-wave blocks regress. LESSON (R11): direct-w2 regresses.
// LESSON (R4+R7): launch_bounds min-waves arg -> spill. LESSON (R6): never
// reinterpret-cast local arrays.

#define NPTS 8192
#define THRESH 0.001f

__global__ void geblnet_setup(const float* __restrict__ w2,
                              float4* __restrict__ CTt) {
    int j = blockIdx.x * blockDim.x + threadIdx.x;
    if (j >= 12 * 169) return;
    int u = j / 169, it = j % 169;
    const float* W = w2 + u * 25 * 25 * 2;
#define WR(v, w) W[((v) * 25 + (w)) * 2]
#define WI(v, w) W[((v) * 25 + (w)) * 2 + 1]
    float c0, c1, c2, c3;
    if (it < 78) {                       // S pairs, a<=b
        int q = it, a = 0;
        while (q >= 12 - a) { q -= 12 - a; ++a; }
        int b = a + q;
        float ar = WR(a, b) + (a != b ? WR(b, a) : 0.f);
        float ai = WI(a, b) + (a != b ? WI(b, a) : 0.f);
        float br = WR(12 + a, 12 + b) + (a != b ? WR(12 + b, 12 + a) : 0.f);
        float bi = WI(12 + a, 12 + b) + (a != b ? WI(12 + b, 12 + a) : 0.f);
        c0 = ar + br; c1 = bi - ai; c2 = ai + bi; c3 = ar - br;
    } else if (it < 156) {               // Hm pairs, a<=b
        int q = it - 78, a = 0;
        while (q >= 12 - a) { q -= 12 - a; ++a; }
        int b = a + q;
        if (a != b) {
            float gr = WR(a, 12 + b) + WR(12 + b, a);
            float gi = WI(a, 12 + b) + WI(12 + b, a);
            float dr = WR(b, 12 + a) + WR(12 + a, b);
            float di = WI(b, 12 + a) + WI(12 + a, b);
            c0 = gr + dr; c1 = di - gi; c2 = gi + di; c3 = gr - dr;
        } else {
            float er = WR(a, 12 + a) + WR(12 + a, a);
            float ei = WI(a, 12 + a) + WI(12 + a, a);
            c0 = er; c1 = 0.f; c2 = ei; c3 = 0.f;
        }
    } else if (it < 168) {               // trace terms
        int a = it - 156;
        float fr = WR(a, 24) + WR(24, a), fi = WI(a, 24) + WI(24, a);
        float pr = WR(12 + a, 24) + WR(24, 12 + a);
        float pi = WI(12 + a, 24) + WI(24, 12 + a);
        c0 = fr + pr; c1 = pi - fi; c2 = fi + pi; c3 = fr - pr;
    } else {                             // unit-unit
        c0 = 3.f * WR(24, 24); c1 = 0.f; c2 = 3.f * WI(24, 24); c3 = 0.f;
    }
    CTt[it * 12 + u] = make_float4(c0, c1, c2, c3);
#undef WR
#undef WI
}

__global__ __launch_bounds__(64) void geblnet_main(
    const float2* __restrict__ x2,      // (8192, 10, 9) complex
    const float2* __restrict__ w1g,     // (12,13,13) complex
    const float* __restrict__ dw,       // (24,)
    const float* __restrict__ db,       // (1,)
    const float4* __restrict__ CTt,     // (169,12)
    float* __restrict__ out)            // (8192,)
{
    // Overlay: phases 1-2 = We row-major (13 ch incl. identity, stride 10);
    //          phases 4-5 = GV[169].
    __shared__ float2 WeGV[170];        //  1360 B
    __shared__ float2 Bs[1560];         // 12480 B: B[u][v][jk], rows pad 10
    __shared__ float2 Hs[108];          //   864 B
    __shared__ float2 Tpar[60];         //   480 B
    __shared__ float2 tr1[12];          //    96 B
    __shared__ float  sc1[12];          //    48 B
    __shared__ float  gb[12];           //    48 B
    __shared__ float  tra[12];          //    48 B

    const int t = threadIdx.x;
    const int p = blockIdx.x;

    // ---- phase 1: build We channels 0..12 (12 data + identity), stride 10
    for (int j = t; j < 117; j += 64) {
        int v = j / 9, ik = j - v * 9;
        int i = ik / 3, jj = ik - i * 3;
        float2 val;
        if (v < 6) val = x2[(size_t)p * 90 + (4 + v) * 9 + ik];
        else if (v < 12) {
            float2 s = x2[(size_t)p * 90 + (v - 2) * 9 + jj * 3 + i];
            val = make_float2(s.x, -s.y);
        } else val = make_float2((i == jj) ? 1.f : 0.f, 0.f);
        WeGV[v * 10 + ik] = val;
    }
    __syncthreads();

    // ---- phase 2a: B[u,v,jk] = sum_w w1[u,v,w] * We[w,jk]; 1404 jobs
    #pragma unroll 1
    for (int e = t; e < 1404; e += 64) {
        int u = e / 117, rem = e - u * 117;
        int v = rem / 9, jk = rem - v * 9;
        const float2* cp = w1g + (u * 13 + v) * 13;
        float br = 0.f, bi = 0.f;
        #pragma unroll
        for (int w = 0; w < 13; ++w) {
            float2 cc = cp[w];
            float2 ee = WeGV[w * 10 + jk];
            br += cc.x * ee.x - cc.y * ee.y;
            bi += cc.x * ee.y + cc.y * ee.x;
        }
        Bs[(u * 13 + v) * 10 + jk] = make_float2(br, bi);
    }
    __syncthreads();

    // ---- phase 2b: H[u,ik] = sum_{v,j} We[v,i,j] * B[u,v,j*3+k]; 108 jobs
    #pragma unroll 1
    for (int e = t; e < 108; e += 64) {
        int u = e / 9, ik = e - u * 9;
        int i = ik / 3, k = ik - i * 3;
        float hr = 0.f, hi = 0.f;
        #pragma unroll
        for (int v = 0; v < 13; ++v) {
            const float2* a = &WeGV[v * 10 + i * 3];
            const float2* b = &Bs[(u * 13 + v) * 10 + k];
            #pragma unroll
            for (int j = 0; j < 3; ++j) {
                float2 aj = a[j];
                float2 bj = b[j * 3];
                hr += aj.x * bj.x - aj.y * bj.y;
                hi += aj.x * bj.y + aj.y * bj.x;
            }
        }
        Hs[u * 9 + ik] = make_float2(hr, hi);
    }
    __syncthreads();

    // ---- phase 3: traces + gerelu + trnorm scales
    if (t < 12) {
        float2 a = Hs[t * 9 + 0], b = Hs[t * 9 + 4], c = Hs[t * 9 + 8];
        float2 tt = make_float2(a.x + b.x + c.x, a.y + b.y + c.y);
        tr1[t] = tt;
        float gg = tt.x > 0.f ? tt.x : 0.f;
        gb[t] = gg;
        tra[t] = gg * sqrtf(tt.x * tt.x + tt.y * tt.y);
    }
    __syncthreads();
    if (t < 12) {
        float m = 0.f;
        #pragma unroll
        for (int u = 0; u < 12; ++u) m += tra[u];
        sc1[t] = gb[t] / fmaxf(m * (1.f / 12.f), THRESH);
    }
    __syncthreads();

    // ---- phase 4: Gram values -> GV (overlays We row-major; dead now)
    for (int it = t; it < 169; it += 64) {
        float2 val;
        if (it < 156) {
            int q = it < 78 ? it : it - 78;
            float fs = sqrtf(625.0f - 8.0f * (float)q);   // exact at bucket edges
            int a = (int)((25.0f - fs) * 0.5f);
            int b = q - (a * (25 - a)) / 2 + a;
            const float2* Ha = &Hs[a * 9];
            const float2* Hb = &Hs[b * 9];
            float s = sc1[a] * sc1[b];
            float vr = 0.f, vi = 0.f;
            if (it < 78) {                    // S = tr(Aa Ab)
                #pragma unroll
                for (int i = 0; i < 3; ++i)
                    #pragma unroll
                    for (int jj = 0; jj < 3; ++jj) {
                        float2 A = Ha[i * 3 + jj], B = Hb[jj * 3 + i];
                        vr += A.x * B.x - A.y * B.y;
                        vi += A.x * B.y + A.y * B.x;
                    }
            } else {                          // Hm = tr(Aa Ab^H)
                #pragma unroll
                for (int e = 0; e < 9; ++e) {
                    float2 A = Ha[e], B = Hb[e];
                    vr += A.x * B.x + A.y * B.y;
                    vi += A.y * B.x - A.x * B.y;
                }
            }
            val = make_float2(s * vr, s * vi);
        } else if (it < 168) {
            int a = it - 156;
            float s = sc1[a]; float2 tt = tr1[a];
            val = make_float2(s * tt.x, s * tt.y);
        } else {
            val = make_float2(1.f, 0.f);
        }
        WeGV[it] = val;
    }
    __syncthreads();

    // ---- phase 5: coefficient contraction, lane=(q,u), 60 active
    if (t < 60) {
        int q = t / 12, u = t - q * 12;
        int i0 = q * 34, i1 = (q == 4) ? 169 : i0 + 34;
        float tre = 0.f, tim = 0.f;
        for (int it = i0; it < i1; ++it) {
            float4 c = CTt[it * 12 + u];
            float2 gv = WeGV[it];
            tre += c.x * gv.x + c.y * gv.y;
            tim += c.z * gv.x + c.w * gv.y;
        }
        Tpar[u * 5 + q] = make_float2(tre, tim);
    }
    __syncthreads();

    // ---- phase 6: layer-2 gerelu + trnorm + dense head
    if (t < 12) {
        float2 tt = make_float2(0.f, 0.f);
        #pragma unroll
        for (int q = 0; q < 5; ++q) {
            float2 A = Tpar[t * 5 + q];
            tt.x += A.x; tt.y += A.y;
        }
        tr1[t] = tt;
        float g = tt.x > 0.f ? tt.x : 0.f;
        gb[t] = g;
        tra[t] = g * sqrtf(tt.x * tt.x + tt.y * tt.y);
    }
    __syncthreads();
    if (t == 0) {
        float m = 0.f;
        #pragma unroll
        for (int u = 0; u < 12; ++u) m += tra[u];
        float inv = 1.f / fmaxf(m * (1.f / 12.f), THRESH);
        float acc = db[0];
        #pragma unroll
        for (int u = 0; u < 12; ++u) {
            float s = gb[u] * inv * (1.f / 3.f);
            acc += s * (tr1[u].x * dw[2 * u] + tr1[u].y * dw[2 * u + 1]);
        }
        out[p] = acc;
    }
}

extern "C" void kernel_launch(void* const* d_in, const int* in_sizes, int n_in,
                              void* d_out, int out_size, void* d_ws, size_t ws_size,
                              hipStream_t stream) {
    const float* x  = (const float*)d_in[0];
    const float* w1 = (const float*)d_in[1];
    const float* w2 = (const float*)d_in[2];
    const float* dw = (const float*)d_in[3];
    const float* db = (const float*)d_in[4];
    float* outp = (float*)d_out;
    float4* CTt = (float4*)d_ws;          // 12*169*16 B = 32448 B

    geblnet_setup<<<(12 * 169 + 255) / 256, 256, 0, stream>>>(w2, CTt);

    geblnet_main<<<NPTS, 64, 0, stream>>>(
        (const float2*)x, (const float2*)w1, dw, db, CTt, outp);
}

// Round 17
// 131.830 us; speedup vs baseline: 1.1839x; 1.1839x over previous
//
#include <hip/hip_runtime.h>
#include <math.h>

// GEBLNet via Gram-matrix reduction (R17 = R14 + transposed We for 2a).
//   T[u] = sum_{v,w} w2[u,v,w] * tr(We2[v] @ We2[w]) -> 169 unique Gram values,
//   w2 folded per-launch into CTt[169][12] float4 (setup kernel; ~50us
//   bench-vs-main gap is fixed harness overhead, extra dispatch is free).
// Shape (R10/R14-proven): 8192 blocks x 64 threads, 1 wave = 1 point.
// Layer 1 on all 64 lanes, two u-half passes through a 6.2KB LDS B buffer:
//   2a: job=(uu,v,jk): B[uu,v,jk] = sum_w w1[u0+uu,v,w]*WeT[jk,w]
//       WeT is the TRANSPOSED We copy: row jk holds all 13 channels
//       contiguously -> ~7 ds_read_b128 instead of 13 strided ds_read_b64.
//   2b: H[u0+uu,ik] = sum_{v,j} We[v,i,j]*B[uu,v,j*3+k]  (54 jobs, 39 cmacs)
// LESSON (R16): merging the two passes pushes VGPR 44->84 (compiler pipelines
// the longer job loop) and loses 40% occupancy — keep the two-pass shape.
// LESSON (R13/R16): VGPR>64 is the occupancy cliff; keep per-job state tiny.
// LESSON (R15): fine-grained 1-cmac jobs beat wider jobs; Bs pad 10 is fine
// (2-way aliasing is free, m136). LESSON (R12): multi-wave blocks regress.
// LESSON (R11): direct-w2 contraction regresses. LESSON (R4+R7): launch_bounds
// min-waves arg -> spill. LESSON (R6): never reinterpret-cast local arrays.

#define NPTS 8192
#define THRESH 0.001f

__global__ void geblnet_setup(const float* __restrict__ w2,
                              float4* __restrict__ CTt) {
    int j = blockIdx.x * blockDim.x + threadIdx.x;
    if (j >= 12 * 169) return;
    int u = j / 169, it = j % 169;
    const float* W = w2 + u * 25 * 25 * 2;
#define WR(v, w) W[((v) * 25 + (w)) * 2]
#define WI(v, w) W[((v) * 25 + (w)) * 2 + 1]
    float c0, c1, c2, c3;
    if (it < 78) {                       // S pairs, a<=b
        int q = it, a = 0;
        while (q >= 12 - a) { q -= 12 - a; ++a; }
        int b = a + q;
        float ar = WR(a, b) + (a != b ? WR(b, a) : 0.f);
        float ai = WI(a, b) + (a != b ? WI(b, a) : 0.f);
        float br = WR(12 + a, 12 + b) + (a != b ? WR(12 + b, 12 + a) : 0.f);
        float bi = WI(12 + a, 12 + b) + (a != b ? WI(12 + b, 12 + a) : 0.f);
        c0 = ar + br; c1 = bi - ai; c2 = ai + bi; c3 = ar - br;
    } else if (it < 156) {               // Hm pairs, a<=b
        int q = it - 78, a = 0;
        while (q >= 12 - a) { q -= 12 - a; ++a; }
        int b = a + q;
        if (a != b) {
            float gr = WR(a, 12 + b) + WR(12 + b, a);
            float gi = WI(a, 12 + b) + WI(12 + b, a);
            float dr = WR(b, 12 + a) + WR(12 + a, b);
            float di = WI(b, 12 + a) + WI(12 + a, b);
            c0 = gr + dr; c1 = di - gi; c2 = gi + di; c3 = gr - dr;
        } else {
            float er = WR(a, 12 + a) + WR(12 + a, a);
            float ei = WI(a, 12 + a) + WI(12 + a, a);
            c0 = er; c1 = 0.f; c2 = ei; c3 = 0.f;
        }
    } else if (it < 168) {               // trace terms
        int a = it - 156;
        float fr = WR(a, 24) + WR(24, a), fi = WI(a, 24) + WI(24, a);
        float pr = WR(12 + a, 24) + WR(24, 12 + a);
        float pi = WI(12 + a, 24) + WI(24, 12 + a);
        c0 = fr + pr; c1 = pi - fi; c2 = fi + pi; c3 = fr - pr;
    } else {                             // unit-unit
        c0 = 3.f * WR(24, 24); c1 = 0.f; c2 = 3.f * WI(24, 24); c3 = 0.f;
    }
    CTt[it * 12 + u] = make_float4(c0, c1, c2, c3);
#undef WR
#undef WI
}

__global__ __launch_bounds__(64) void geblnet_main(
    const float2* __restrict__ x2,      // (8192, 10, 9) complex
    const float2* __restrict__ w1g,     // (12,13,13) complex
    const float* __restrict__ dw,       // (24,)
    const float* __restrict__ db,       // (1,)
    const float4* __restrict__ CTt,     // (169,12)
    float* __restrict__ out)            // (8192,)
{
    // Overlay: phases 1-2 = We row-major (13 ch incl. identity, stride 10);
    //          phases 4-5 = GV[169].
    __shared__ float2 WeGV[170];        // 1360 B
    // Transposed copy for 2a: WeT[jk][w], rows pad to 14 float2 (16B-aligned).
    __shared__ __align__(16) float2 WeT[9 * 14];   // 1008 B
    __shared__ float2 Bs[780];          // 6240 B: B[uu][v][jk], rows pad 10
    __shared__ float2 Hs[108];          //  864 B
    __shared__ float2 Tpar[60];         //  480 B
    __shared__ float2 tr1[12];          //   96 B
    __shared__ float  sc1[12];          //   48 B
    __shared__ float  gb[12];           //   48 B
    __shared__ float  tra[12];          //   48 B

    const int t = threadIdx.x;
    const int p = blockIdx.x;

    // ---- phase 1: build We channels 0..12 in both layouts
    for (int j = t; j < 117; j += 64) {
        int v = j / 9, ik = j - v * 9;
        int i = ik / 3, jj = ik - i * 3;
        float2 val;
        if (v < 6) val = x2[(size_t)p * 90 + (4 + v) * 9 + ik];
        else if (v < 12) {
            float2 s = x2[(size_t)p * 90 + (v - 2) * 9 + jj * 3 + i];
            val = make_float2(s.x, -s.y);
        } else val = make_float2((i == jj) ? 1.f : 0.f, 0.f);
        WeGV[v * 10 + ik] = val;        // row-major (2b + phase-4 overlay)
        WeT[ik * 14 + v] = val;         // transposed (2a: contiguous w-row)
    }
    __syncthreads();

    // ---- phase 2: layer 1 on all 64 lanes, two u-half passes
    #pragma unroll 1
    for (int g = 0; g < 2; ++g) {
        const int u0 = g * 6;
        // 2a: B[uu][v][jk] = sum_w w1[u0+uu,v,w] * WeT[jk][w]
        #pragma unroll 1
        for (int e = t; e < 702; e += 64) {
            int uu = e / 117, rem = e - uu * 117;
            int v = rem / 9, jk = rem - v * 9;
            const float2* cp = w1g + ((u0 + uu) * 13 + v) * 13;   // contiguous
            const float2* wt = &WeT[jk * 14];                     // contiguous
            float br = 0.f, bi = 0.f;
            #pragma unroll
            for (int w = 0; w < 13; ++w) {
                float2 cc = cp[w];
                float2 ee = wt[w];
                br += cc.x * ee.x - cc.y * ee.y;
                bi += cc.x * ee.y + cc.y * ee.x;
            }
            Bs[(uu * 13 + v) * 10 + jk] = make_float2(br, bi);
        }
        __syncthreads();
        // 2b: H[u0+uu][i][k] = sum_{v,j} We[v][i][j] * B[uu][v][j*3+k]
        if (t < 54) {
            int uu = t / 9, ik = t - uu * 9;
            int i = ik / 3, k = ik - i * 3;
            float hr = 0.f, hi = 0.f;
            #pragma unroll
            for (int v = 0; v < 13; ++v) {
                const float2* a = &WeGV[v * 10 + i * 3];
                const float2* b = &Bs[(uu * 13 + v) * 10 + k];
                #pragma unroll
                for (int j = 0; j < 3; ++j) {
                    float2 aj = a[j];
                    float2 bj = b[j * 3];
                    hr += aj.x * bj.x - aj.y * bj.y;
                    hi += aj.x * bj.y + aj.y * bj.x;
                }
            }
            Hs[(u0 + uu) * 9 + ik] = make_float2(hr, hi);
        }
        __syncthreads();
    }

    // ---- phase 3: traces + gerelu + trnorm scales
    if (t < 12) {
        float2 a = Hs[t * 9 + 0], b = Hs[t * 9 + 4], c = Hs[t * 9 + 8];
        float2 tt = make_float2(a.x + b.x + c.x, a.y + b.y + c.y);
        tr1[t] = tt;
        float gg = tt.x > 0.f ? tt.x : 0.f;
        gb[t] = gg;
        tra[t] = gg * sqrtf(tt.x * tt.x + tt.y * tt.y);
    }
    __syncthreads();
    if (t < 12) {
        float m = 0.f;
        #pragma unroll
        for (int u = 0; u < 12; ++u) m += tra[u];
        sc1[t] = gb[t] / fmaxf(m * (1.f / 12.f), THRESH);
    }
    __syncthreads();

    // ---- phase 4: Gram values -> GV (overlays We row-major; dead now)
    for (int it = t; it < 169; it += 64) {
        float2 val;
        if (it < 156) {
            int q = it < 78 ? it : it - 78;
            float fs = sqrtf(625.0f - 8.0f * (float)q);   // exact at bucket edges
            int a = (int)((25.0f - fs) * 0.5f);
            int b = q - (a * (25 - a)) / 2 + a;
            const float2* Ha = &Hs[a * 9];
            const float2* Hb = &Hs[b * 9];
            float s = sc1[a] * sc1[b];
            float vr = 0.f, vi = 0.f;
            if (it < 78) {                    // S = tr(Aa Ab)
                #pragma unroll
                for (int i = 0; i < 3; ++i)
                    #pragma unroll
                    for (int jj = 0; jj < 3; ++jj) {
                        float2 A = Ha[i * 3 + jj], B = Hb[jj * 3 + i];
                        vr += A.x * B.x - A.y * B.y;
                        vi += A.x * B.y + A.y * B.x;
                    }
            } else {                          // Hm = tr(Aa Ab^H)
                #pragma unroll
                for (int e = 0; e < 9; ++e) {
                    float2 A = Ha[e], B = Hb[e];
                    vr += A.x * B.x + A.y * B.y;
                    vi += A.y * B.x - A.x * B.y;
                }
            }
            val = make_float2(s * vr, s * vi);
        } else if (it < 168) {
            int a = it - 156;
            float s = sc1[a]; float2 tt = tr1[a];
            val = make_float2(s * tt.x, s * tt.y);
        } else {
            val = make_float2(1.f, 0.f);
        }
        WeGV[it] = val;
    }
    __syncthreads();

    // ---- phase 5: coefficient contraction, lane=(q,u), 60 active
    if (t < 60) {
        int q = t / 12, u = t - q * 12;
        int i0 = q * 34, i1 = (q == 4) ? 169 : i0 + 34;
        float tre = 0.f, tim = 0.f;
        for (int it = i0; it < i1; ++it) {
            float4 c = CTt[it * 12 + u];
            float2 gv = WeGV[it];
            tre += c.x * gv.x + c.y * gv.y;
            tim += c.z * gv.x + c.w * gv.y;
        }
        Tpar[u * 5 + q] = make_float2(tre, tim);
    }
    __syncthreads();

    // ---- phase 6: layer-2 gerelu + trnorm + dense head
    if (t < 12) {
        float2 tt = make_float2(0.f, 0.f);
        #pragma unroll
        for (int q = 0; q < 5; ++q) {
            float2 A = Tpar[t * 5 + q];
            tt.x += A.x; tt.y += A.y;
        }
        tr1[t] = tt;
        float g = tt.x > 0.f ? tt.x : 0.f;
        gb[t] = g;
        tra[t] = g * sqrtf(tt.x * tt.x + tt.y * tt.y);
    }
    __syncthreads();
    if (t == 0) {
        float m = 0.f;
        #pragma unroll
        for (int u = 0; u < 12; ++u) m += tra[u];
        float inv = 1.f / fmaxf(m * (1.f / 12.f), THRESH);
        float acc = db[0];
        #pragma unroll
        for (int u = 0; u < 12; ++u) {
            float s = gb[u] * inv * (1.f / 3.f);
            acc += s * (tr1[u].x * dw[2 * u] + tr1[u].y * dw[2 * u + 1]);
        }
        out[p] = acc;
    }
}

extern "C" void kernel_launch(void* const* d_in, const int* in_sizes, int n_in,
                              void* d_out, int out_size, void* d_ws, size_t ws_size,
                              hipStream_t stream) {
    const float* x  = (const float*)d_in[0];
    const float* w1 = (const float*)d_in[1];
    const float* w2 = (const float*)d_in[2];
    const float* dw = (const float*)d_in[3];
    const float* db = (const float*)d_in[4];
    float* outp = (float*)d_out;
    float4* CTt = (float4*)d_ws;          // 12*169*16 B = 32448 B

    geblnet_setup<<<(12 * 169 + 255) / 256, 256, 0, stream>>>(w2, CTt);

    geblnet_main<<<NPTS, 64, 0, stream>>>(
        (const float2*)x, (const float2*)w1, dw, db, CTt, outp);
}